// Round 15
// baseline (195.699 us; speedup 1.0000x reference)
//
#include <hip/hip_runtime.h>
#include <math.h>

#define N_NODES 20000
#define N_EDGES 320000
#define C_IN  256
#define C_HID 256
#define C_OUT 128
#define NEG_SLOPE 0.2f
#define CAP   256   // padded-CSR slots per node (real edges only; self-loop implicit)

typedef __attribute__((ext_vector_type(8))) short bf16x8;
typedef __attribute__((ext_vector_type(4))) float f32x4;

// ---- all scratch in module globals (ws_size unknown; globals are safe) ----
__device__ __align__(16) unsigned short c_W1h[C_IN * C_HID], c_W1l[C_IN * C_HID];
__device__ __align__(16) unsigned short c_W2h[C_HID * C_OUT], c_W2l[C_HID * C_OUT];
__device__ float c_as1f[C_HID], c_ad1f[C_HID], c_b1f[C_HID];
__device__ float c_as2f[C_OUT], c_ad2f[C_OUT], c_b2f[C_OUT];
__device__ __align__(16) unsigned short g_h1b[(size_t)N_NODES * C_HID]; // h1 bf16
__device__ __align__(16) unsigned short g_g1h[(size_t)N_NODES * C_HID]; // relu(agg1) hi
__device__ __align__(16) unsigned short g_g1l[(size_t)N_NODES * C_HID]; // relu(agg1) lo
__device__ __align__(16) unsigned short g_h2b[(size_t)N_NODES * C_OUT]; // h2 bf16
__device__ float g_alps1[N_NODES], g_alpd1[N_NODES];
__device__ float g_alps2[N_NODES], g_alpd2[N_NODES];
__device__ int   g_cursor[N_NODES];            // per-node real-edge count
__device__ int   g_srcidx[(size_t)N_NODES * CAP];
__device__ int   g_is64;    // edge_index arrived as raw int64 words
__device__ int   g_isf32;   // float inputs arrived as raw fp32 words

__device__ __forceinline__ float bf2f(unsigned short b){
  unsigned int u = ((unsigned int)b) << 16;
  return __builtin_bit_cast(float, u);
}
__device__ __forceinline__ unsigned short f2bf(float f){
  unsigned int u = __builtin_bit_cast(unsigned int, f);
  u += 0x7fffu + ((u >> 16) & 1u);   // round-to-nearest-even
  return (unsigned short)(u >> 16);
}
__device__ __forceinline__ int clampi(int v){
  v = v < 0 ? 0 : v;
  return v >= N_NODES ? N_NODES - 1 : v;
}
__device__ __forceinline__ void edge_sd(const int* ei, int e, int& s, int& d){
  if (g_is64){ s = ei[2 * e]; d = ei[2 * (N_EDGES + e)]; }
  else       { s = ei[e];     d = ei[N_EDGES + e]; }
  s = clampi(s); d = clampi(d);
}

struct Ptrs { const void* p[8]; };

// pack (k, n) of a [K][Nc] weight into MFMA B-fragment order
__device__ __forceinline__ int wpack(int k, int n, int Nc){
  return (((k >> 5) * (Nc / 16) + (n >> 4)) * 64 + (((k >> 3) & 3) * 16 + (n & 15))) * 8 + (k & 7);
}

// =======================================================================
// prep_k: probe publish + zero accumulators + weight pack, ONE dispatch.
// =======================================================================
#define PREP_Z  N_NODES
#define PREP_W1 (C_IN * C_HID)
#define PREP_W2 (C_HID * C_OUT)
#define PREP_T  (PREP_Z + PREP_W1 + PREP_W2 + 2 * C_HID + C_HID + 2 * C_OUT + C_OUT)

__global__ void prep_k(const unsigned int* __restrict__ xw,
                       const int* __restrict__ ei, Ptrs ps){
  __shared__ int s_isf32;
  if (threadIdx.x < 64){
    int lane = (int)threadIdx.x, cnt = 0;
    for (int j = lane; j < 256; j += 64){
      unsigned int e = (xw[j] >> 7) & 0xFFu;
      if (e >= 0x60u && e <= 0x8Fu) ++cnt;
    }
#pragma unroll
    for (int o = 32; o > 0; o >>= 1) cnt += __shfl_xor(cnt, o, 64);
    if (lane == 0) s_isf32 = (cnt < 200) ? 1 : 0;  // bf16 ~256 in-win; fp32 ~48
  }
  __syncthreads();
  const int isf32 = s_isf32;

  if (blockIdx.x == 0 && threadIdx.x < 64){        // publish for later dispatches
    unsigned long long anybad = __ballot(ei[2 * (int)threadIdx.x + 1] != 0);
    if (threadIdx.x == 0){ g_isf32 = isf32; g_is64 = (anybad == 0ULL) ? 1 : 0; }
  }

  int tid = (int)(blockIdx.x * blockDim.x + threadIdx.x);
  if (tid < PREP_Z){
    g_cursor[tid] = 0;
    g_alps1[tid] = 0.f; g_alpd1[tid] = 0.f;
    g_alps2[tid] = 0.f; g_alpd2[tid] = 0.f;
    return;
  }
  int j = tid - PREP_Z;
  auto ld = [&](const void* p, int i) -> float {
    return isf32 ? ((const float*)p)[i] : bf2f(((const unsigned short*)p)[i]);
  };
  if (j < PREP_W1){
    float f = ld(ps.p[0], j);
    int k = j / C_HID, n = j % C_HID;
    int idx = wpack(k, n, C_HID);
    unsigned short h = f2bf(f);
    c_W1h[idx] = h; c_W1l[idx] = f2bf(f - bf2f(h));
    return;
  }
  j -= PREP_W1;
  if (j < PREP_W2){
    float f = ld(ps.p[4], j);
    int k = j / C_OUT, n = j % C_OUT;
    int idx = wpack(k, n, C_OUT);
    unsigned short h = f2bf(f);
    c_W2h[idx] = h; c_W2l[idx] = f2bf(f - bf2f(h));
    return;
  }
  j -= PREP_W2;
  if      (j <  256) c_as1f[j]        = ld(ps.p[1], j);
  else if (j <  512) c_ad1f[j - 256]  = ld(ps.p[2], j - 256);
  else if (j <  768) c_b1f [j - 512]  = ld(ps.p[3], j - 512);
  else if (j <  896) c_as2f[j - 768]  = ld(ps.p[5], j - 768);
  else if (j < 1024) c_ad2f[j - 896]  = ld(ps.p[6], j - 896);
  else if (j < 1152) c_b2f [j - 1024] = ld(ps.p[7], j - 1024);
}

// ---------------- padded-CSR scatter: real edges only (self-loops implicit) ----------------
__global__ void scatter_k(const int* __restrict__ ei){
  int e = blockIdx.x * blockDim.x + threadIdx.x;
  if (e >= N_EDGES) return;
  int s, d;
  edge_sd(ei, e, s, d);
  int pos = atomicAdd(&g_cursor[d], 1);
  if (pos < CAP) g_srcidx[(size_t)d * CAP + pos] = s;  // clamp: memory-safe
}

// ---------------- split-bf16 MFMA GEMM + fused alpha epilogue (R13-proven) ----------------
template<int SEL>
__global__ __launch_bounds__(256) void gemm_k(const void* __restrict__ xsrc){
  const int Nc = SEL ? C_OUT : C_HID;
  const int NT = SEL ? 2 : 4;
  const unsigned short* Wh = SEL ? c_W2h : c_W1h;
  const unsigned short* Wl = SEL ? c_W2l : c_W1l;
  unsigned short* Hb = SEL ? g_h2b : g_h1b;
  float* alps = SEL ? g_alps2 : g_alps1;
  float* alpd = SEL ? g_alpd2 : g_alpd1;
  const float* aS = SEL ? c_as2f : c_as1f;
  const float* aD = SEL ? c_ad2f : c_ad1f;
  const bool isf32 = (SEL == 0) && (g_isf32 != 0);

  int wave = (int)(threadIdx.x >> 6);
  int lane = (int)(threadIdx.x & 63);
  int kgrp = lane >> 4, cl = lane & 15;
  int mbase = blockIdx.x * 32;

  f32x4 acc[2][4];
#pragma unroll
  for (int m = 0; m < 2; ++m)
#pragma unroll
    for (int n = 0; n < NT; ++n) acc[m][n] = (f32x4){0.f, 0.f, 0.f, 0.f};

  for (int kt = 0; kt < 8; ++kt){
    int kbase = kt * 32 + kgrp * 8;
    bf16x8 ah[2], al[2];
    if (SEL == 1){
#pragma unroll
      for (int m = 0; m < 2; ++m){
        size_t ai = (size_t)(mbase + m * 16 + cl) * 256 + kbase;
        ah[m] = *(const bf16x8*)(g_g1h + ai);
        al[m] = *(const bf16x8*)(g_g1l + ai);
      }
    } else if (isf32){
      const float* Xf = (const float*)xsrc;
#pragma unroll
      for (int m = 0; m < 2; ++m){
        const float4* xp = (const float4*)(Xf + (size_t)(mbase + m * 16 + cl) * 256 + kbase);
        float4 v0 = xp[0], v1 = xp[1];
        float vals[8] = {v0.x, v0.y, v0.z, v0.w, v1.x, v1.y, v1.z, v1.w};
#pragma unroll
        for (int j = 0; j < 8; ++j){
          unsigned short h = f2bf(vals[j]);
          ah[m][j] = (short)h;
          al[m][j] = (short)f2bf(vals[j] - bf2f(h));
        }
      }
    } else {  // bf16 input: lo part is zero
      const unsigned short* Xb = (const unsigned short*)xsrc;
#pragma unroll
      for (int m = 0; m < 2; ++m){
        ah[m] = *(const bf16x8*)(Xb + (size_t)(mbase + m * 16 + cl) * 256 + kbase);
        al[m] = (bf16x8){0,0,0,0,0,0,0,0};
      }
    }
#pragma unroll
    for (int nn = 0; nn < NT; ++nn){
      int nt = wave * NT + nn;
      size_t wi = ((size_t)(kt * (Nc / 16) + nt) * 64 + lane) * 8;
      bf16x8 bh = *(const bf16x8*)(Wh + wi);
      bf16x8 bl = *(const bf16x8*)(Wl + wi);
#pragma unroll
      for (int m = 0; m < 2; ++m){
        acc[m][nn] = __builtin_amdgcn_mfma_f32_16x16x32_bf16(ah[m], bh, acc[m][nn], 0, 0, 0);
        acc[m][nn] = __builtin_amdgcn_mfma_f32_16x16x32_bf16(ah[m], bl, acc[m][nn], 0, 0, 0);
        acc[m][nn] = __builtin_amdgcn_mfma_f32_16x16x32_bf16(al[m], bh, acc[m][nn], 0, 0, 0);
      }
    }
  }

  float asv[4], adv[4];
#pragma unroll
  for (int nn = 0; nn < NT; ++nn){
    int col = (wave * NT + nn) * 16 + cl;
    asv[nn] = aS[col]; adv[nn] = aD[col];
  }
#pragma unroll
  for (int m = 0; m < 2; ++m){
#pragma unroll
    for (int i = 0; i < 4; ++i){
      int row = mbase + m * 16 + kgrp * 4 + i;
      float ps = 0.f, pd = 0.f;
#pragma unroll
      for (int nn = 0; nn < NT; ++nn){
        int col = (wave * NT + nn) * 16 + cl;
        float v = acc[m][nn][i];
        Hb[(size_t)row * Nc + col] = f2bf(v);
        ps += v * asv[nn]; pd += v * adv[nn];
      }
      ps += __shfl_xor(ps, 1);  pd += __shfl_xor(pd, 1);
      ps += __shfl_xor(ps, 2);  pd += __shfl_xor(pd, 2);
      ps += __shfl_xor(ps, 4);  pd += __shfl_xor(pd, 4);
      ps += __shfl_xor(ps, 8);  pd += __shfl_xor(pd, 8);
      if (cl == 0){
        atomicAdd(&alps[row], ps);
        atomicAdd(&alpd[row], pd);
      }
    }
  }
}

// ---------------- fused softmax + aggregation: TWO waves per node ----------------
// Each wave runs the R13-proven full-wave gather loop over HALF the node's
// edge range (halves the serial latency chain); partials combined via LDS.
// Self-loop handled analytically by the even wave.
#define ACC4(p, ww) { \
  a0 += (ww) * bf2f((unsigned short)((p).x & 0xFFFFu)); \
  a1 += (ww) * bf2f((unsigned short)((p).x >> 16)); \
  a2 += (ww) * bf2f((unsigned short)((p).y & 0xFFFFu)); \
  a3 += (ww) * bf2f((unsigned short)((p).y >> 16)); }

#define ACC2(p, ww) { \
  a0 += (ww) * bf2f((unsigned short)((p) & 0xFFFFu)); \
  a1 += (ww) * bf2f((unsigned short)((p) >> 16)); }

template<int F, int SEL>
__global__ __launch_bounds__(256) void agg_k(float* OUT){
  const unsigned short* Hb = SEL ? g_h2b : g_h1b;
  const float* bias = SEL ? c_b2f : c_b1f;
  const float* alps = SEL ? g_alps2 : g_alps1;
  const float* alpd = SEL ? g_alpd2 : g_alpd1;
  __shared__ float lds_a[4][64][4];
  __shared__ float lds_d[4][64];

  int lane = threadIdx.x & 63;
  int wv   = (int)(threadIdx.x >> 6);      // 0..3
  int half = wv & 1;                       // which half of the edge range
  int n = blockIdx.x * 2 + (wv >> 1);

  int len = g_cursor[n]; if (len > CAP) len = CAP;
  int lenA = len >> 1;
  int i0 = n * CAP + (half ? lenA : 0);
  int i1 = n * CAP + (half ? len : lenA);
  float adn = alpd[n];
  float dpart = 0.f;
  float a0 = 0.f, a1 = 0.f, a2 = 0.f, a3 = 0.f;
  const uint2* H2 = (const uint2*)Hb;          // F=256: lane owns 4 feats
  const unsigned int* H1 = (const unsigned int*)Hb; // F=128: lane owns 2 feats

  if (half == 0){  // implicit self-loop: source row = n
    float es = alps[n] + adn;
    es = (es > 0.f) ? es : NEG_SLOPE * es;
    float wself = __expf(es);
    if (lane == 0) dpart += wself;
    if constexpr (F == 256){
      uint2 p = H2[(size_t)n * 64 + lane];
      ACC4(p, wself)
    } else {
      unsigned int p = H1[(size_t)n * 64 + lane];
      ACC2(p, wself)
    }
  }

  for (int base = i0; base < i1; base += 64){
    int nv = i1 - base; if (nv > 64) nv = 64;
    int sv = 0; float wvv = 0.f;
    if (lane < nv){
      sv = g_srcidx[base + lane];
      float e = alps[sv] + adn;
      e = (e > 0.f) ? e : NEG_SLOPE * e;
      wvv = __expf(e);
    }
    dpart += wvv;
    int j = 0;
    for (; j + 8 <= nv; j += 8){
      int s0 = __shfl(sv, j),     s1 = __shfl(sv, j + 1);
      int s2 = __shfl(sv, j + 2), s3 = __shfl(sv, j + 3);
      int s4 = __shfl(sv, j + 4), s5 = __shfl(sv, j + 5);
      int s6 = __shfl(sv, j + 6), s7 = __shfl(sv, j + 7);
      float w0 = __shfl(wvv, j),     w1 = __shfl(wvv, j + 1);
      float w2 = __shfl(wvv, j + 2), w3 = __shfl(wvv, j + 3);
      float w4 = __shfl(wvv, j + 4), w5 = __shfl(wvv, j + 5);
      float w6 = __shfl(wvv, j + 6), w7 = __shfl(wvv, j + 7);
      if constexpr (F == 256){
        uint2 p0 = H2[(size_t)s0 * 64 + lane];
        uint2 p1 = H2[(size_t)s1 * 64 + lane];
        uint2 p2 = H2[(size_t)s2 * 64 + lane];
        uint2 p3 = H2[(size_t)s3 * 64 + lane];
        uint2 p4 = H2[(size_t)s4 * 64 + lane];
        uint2 p5 = H2[(size_t)s5 * 64 + lane];
        uint2 p6 = H2[(size_t)s6 * 64 + lane];
        uint2 p7 = H2[(size_t)s7 * 64 + lane];
        ACC4(p0, w0) ACC4(p1, w1) ACC4(p2, w2) ACC4(p3, w3)
        ACC4(p4, w4) ACC4(p5, w5) ACC4(p6, w6) ACC4(p7, w7)
      } else {
        unsigned int p0 = H1[(size_t)s0 * 64 + lane];
        unsigned int p1 = H1[(size_t)s1 * 64 + lane];
        unsigned int p2 = H1[(size_t)s2 * 64 + lane];
        unsigned int p3 = H1[(size_t)s3 * 64 + lane];
        unsigned int p4 = H1[(size_t)s4 * 64 + lane];
        unsigned int p5 = H1[(size_t)s5 * 64 + lane];
        unsigned int p6 = H1[(size_t)s6 * 64 + lane];
        unsigned int p7 = H1[(size_t)s7 * 64 + lane];
        ACC2(p0, w0) ACC2(p1, w1) ACC2(p2, w2) ACC2(p3, w3)
        ACC2(p4, w4) ACC2(p5, w5) ACC2(p6, w6) ACC2(p7, w7)
      }
    }
    for (; j + 4 <= nv; j += 4){
      int s0 = __shfl(sv, j),     s1 = __shfl(sv, j + 1);
      int s2 = __shfl(sv, j + 2), s3 = __shfl(sv, j + 3);
      float w0 = __shfl(wvv, j),     w1 = __shfl(wvv, j + 1);
      float w2 = __shfl(wvv, j + 2), w3 = __shfl(wvv, j + 3);
      if constexpr (F == 256){
        uint2 p0 = H2[(size_t)s0 * 64 + lane];
        uint2 p1 = H2[(size_t)s1 * 64 + lane];
        uint2 p2 = H2[(size_t)s2 * 64 + lane];
        uint2 p3 = H2[(size_t)s3 * 64 + lane];
        ACC4(p0, w0) ACC4(p1, w1) ACC4(p2, w2) ACC4(p3, w3)
      } else {
        unsigned int p0 = H1[(size_t)s0 * 64 + lane];
        unsigned int p1 = H1[(size_t)s1 * 64 + lane];
        unsigned int p2 = H1[(size_t)s2 * 64 + lane];
        unsigned int p3 = H1[(size_t)s3 * 64 + lane];
        ACC2(p0, w0) ACC2(p1, w1) ACC2(p2, w2) ACC2(p3, w3)
      }
    }
    for (; j < nv; ++j){
      int s = __shfl(sv, j);
      float w = __shfl(wvv, j);
      if constexpr (F == 256){
        uint2 p = H2[(size_t)s * 64 + lane];
        ACC4(p, w)
      } else {
        unsigned int p = H1[(size_t)s * 64 + lane];
        ACC2(p, w)
      }
    }
  }

  // combine the two half-range waves via LDS
  lds_a[wv][lane][0] = a0; lds_a[wv][lane][1] = a1;
  lds_a[wv][lane][2] = a2; lds_a[wv][lane][3] = a3;
  lds_d[wv][lane] = dpart;
  __syncthreads();
  if (half) return;
  a0 += lds_a[wv + 1][lane][0]; a1 += lds_a[wv + 1][lane][1];
  a2 += lds_a[wv + 1][lane][2]; a3 += lds_a[wv + 1][lane][3];
  float den = dpart + lds_d[wv + 1][lane];
#pragma unroll
  for (int o = 32; o > 0; o >>= 1) den += __shfl_xor(den, o, 64);
  float inv = 1.f / den;

  if constexpr (F == 256){
    float o0 = a0 * inv + bias[4 * lane];
    float o1 = a1 * inv + bias[4 * lane + 1];
    float o2 = a2 * inv + bias[4 * lane + 2];
    float o3 = a3 * inv + bias[4 * lane + 3];
    if (SEL == 0){
      o0 = fmaxf(o0, 0.f); o1 = fmaxf(o1, 0.f);
      o2 = fmaxf(o2, 0.f); o3 = fmaxf(o3, 0.f);
      unsigned short h0 = f2bf(o0), h1 = f2bf(o1), h2 = f2bf(o2), h3 = f2bf(o3);
      uint2 ph, pl;
      ph.x = (unsigned)h0 | ((unsigned)h1 << 16);
      ph.y = (unsigned)h2 | ((unsigned)h3 << 16);
      pl.x = (unsigned)f2bf(o0 - bf2f(h0)) | ((unsigned)f2bf(o1 - bf2f(h1)) << 16);
      pl.y = (unsigned)f2bf(o2 - bf2f(h2)) | ((unsigned)f2bf(o3 - bf2f(h3)) << 16);
      ((uint2*)g_g1h)[(size_t)n * 64 + lane] = ph;
      ((uint2*)g_g1l)[(size_t)n * 64 + lane] = pl;
    } else {
      float4 o; o.x = o0; o.y = o1; o.z = o2; o.w = o3;
      ((float4*)OUT)[(size_t)n * 64 + lane] = o;
    }
  } else {
    float o0 = a0 * inv + bias[2 * lane];
    float o1 = a1 * inv + bias[2 * lane + 1];
    if (SEL == 0){
      o0 = fmaxf(o0, 0.f); o1 = fmaxf(o1, 0.f);
      unsigned short h0 = f2bf(o0), h1 = f2bf(o1);
      ((unsigned int*)g_g1h)[(size_t)n * 64 + lane] = (unsigned)h0 | ((unsigned)h1 << 16);
      ((unsigned int*)g_g1l)[(size_t)n * 64 + lane] =
        (unsigned)f2bf(o0 - bf2f(h0)) | ((unsigned)f2bf(o1 - bf2f(h1)) << 16);
    } else {
      float2 o; o.x = o0; o.y = o1;
      ((float2*)OUT)[(size_t)n * 64 + lane] = o;
    }
  }
}

extern "C" void kernel_launch(void* const* d_in, const int* in_sizes, int n_in,
                              void* d_out, int out_size, void* d_ws, size_t ws_size,
                              hipStream_t stream){
  (void)in_sizes; (void)n_in; (void)out_size; (void)d_ws; (void)ws_size;
  const void* x  = d_in[0];
  const int*  ei = (const int*)d_in[1];
  float* out = (float*)d_out;

  Ptrs ps;
  ps.p[0] = d_in[2]; ps.p[1] = d_in[3]; ps.p[2] = d_in[4]; ps.p[3] = d_in[5];
  ps.p[4] = d_in[6]; ps.p[5] = d_in[7]; ps.p[6] = d_in[8]; ps.p[7] = d_in[9];

  prep_k<<<(PREP_T + 255) / 256, 256, 0, stream>>>((const unsigned int*)x, ei, ps);
  scatter_k<<<(N_EDGES + 255) / 256, 256, 0, stream>>>(ei);

  // ---- layer 1 ----
  gemm_k<0><<<N_NODES / 32, 256, 0, stream>>>(x);
  agg_k<C_HID, 0><<<N_NODES / 2, 256, 0, stream>>>(nullptr);

  // ---- layer 2 ----
  gemm_k<1><<<N_NODES / 32, 256, 0, stream>>>(nullptr);
  agg_k<C_OUT, 1><<<N_NODES / 2, 256, 0, stream>>>(out);
}

// Round 16
// 183.970 us; speedup vs baseline: 1.0638x; 1.0638x over previous
//
#include <hip/hip_runtime.h>
#include <math.h>

#define N_NODES 20000
#define N_EDGES 320000
#define C_IN  256
#define C_HID 256
#define C_OUT 128
#define NEG_SLOPE 0.2f
#define CAP   256   // padded-CSR slots per node (real edges only; self-loop implicit)
#define GEMM1_BLKS (N_NODES / 32)          // 625
#define SCAT_BLKS  ((N_EDGES + 255) / 256) // 1250

typedef __attribute__((ext_vector_type(8))) short bf16x8;
typedef __attribute__((ext_vector_type(4))) float f32x4;

// ---- all scratch in module globals (ws_size unknown; globals are safe) ----
__device__ __align__(16) unsigned short c_W1h[C_IN * C_HID], c_W1l[C_IN * C_HID];
__device__ __align__(16) unsigned short c_W2h[C_HID * C_OUT], c_W2l[C_HID * C_OUT];
__device__ float c_as1f[C_HID], c_ad1f[C_HID], c_b1f[C_HID];
__device__ float c_as2f[C_OUT], c_ad2f[C_OUT], c_b2f[C_OUT];
__device__ __align__(16) unsigned short g_h1b[(size_t)N_NODES * C_HID]; // h1 bf16
__device__ __align__(16) unsigned short g_g1h[(size_t)N_NODES * C_HID]; // relu(agg1) hi
__device__ __align__(16) unsigned short g_g1l[(size_t)N_NODES * C_HID]; // relu(agg1) lo
__device__ __align__(16) unsigned short g_h2b[(size_t)N_NODES * C_OUT]; // h2 bf16
__device__ float g_alps1[N_NODES], g_alpd1[N_NODES];
__device__ float g_alps2[N_NODES], g_alpd2[N_NODES];
__device__ int   g_cursor[N_NODES];            // per-node real-edge count
__device__ int   g_srcidx[(size_t)N_NODES * CAP];
__device__ int   g_is64;    // edge_index arrived as raw int64 words
__device__ int   g_isf32;   // float inputs arrived as raw fp32 words

__device__ __forceinline__ float bf2f(unsigned short b){
  unsigned int u = ((unsigned int)b) << 16;
  return __builtin_bit_cast(float, u);
}
__device__ __forceinline__ unsigned short f2bf(float f){
  unsigned int u = __builtin_bit_cast(unsigned int, f);
  u += 0x7fffu + ((u >> 16) & 1u);   // round-to-nearest-even
  return (unsigned short)(u >> 16);
}
__device__ __forceinline__ int clampi(int v){
  v = v < 0 ? 0 : v;
  return v >= N_NODES ? N_NODES - 1 : v;
}
__device__ __forceinline__ void edge_sd(const int* ei, int e, int& s, int& d){
  if (g_is64){ s = ei[2 * e]; d = ei[2 * (N_EDGES + e)]; }
  else       { s = ei[e];     d = ei[N_EDGES + e]; }
  s = clampi(s); d = clampi(d);
}

struct Ptrs { const void* p[8]; };

// pack (k, n) of a [K][Nc] weight into MFMA B-fragment order
__device__ __forceinline__ int wpack(int k, int n, int Nc){
  return (((k >> 5) * (Nc / 16) + (n >> 4)) * 64 + (((k >> 3) & 3) * 16 + (n & 15))) * 8 + (k & 7);
}

// =======================================================================
// prep_k: probe publish + zero accumulators + weight pack, ONE dispatch.
// =======================================================================
#define PREP_Z  N_NODES
#define PREP_W1 (C_IN * C_HID)
#define PREP_W2 (C_HID * C_OUT)
#define PREP_T  (PREP_Z + PREP_W1 + PREP_W2 + 2 * C_HID + C_HID + 2 * C_OUT + C_OUT)

__global__ void prep_k(const unsigned int* __restrict__ xw,
                       const int* __restrict__ ei, Ptrs ps){
  __shared__ int s_isf32;
  if (threadIdx.x < 64){
    int lane = (int)threadIdx.x, cnt = 0;
    for (int j = lane; j < 256; j += 64){
      unsigned int e = (xw[j] >> 7) & 0xFFu;
      if (e >= 0x60u && e <= 0x8Fu) ++cnt;
    }
#pragma unroll
    for (int o = 32; o > 0; o >>= 1) cnt += __shfl_xor(cnt, o, 64);
    if (lane == 0) s_isf32 = (cnt < 200) ? 1 : 0;  // bf16 ~256 in-win; fp32 ~48
  }
  __syncthreads();
  const int isf32 = s_isf32;

  if (blockIdx.x == 0 && threadIdx.x < 64){        // publish for later dispatches
    unsigned long long anybad = __ballot(ei[2 * (int)threadIdx.x + 1] != 0);
    if (threadIdx.x == 0){ g_isf32 = isf32; g_is64 = (anybad == 0ULL) ? 1 : 0; }
  }

  int tid = (int)(blockIdx.x * blockDim.x + threadIdx.x);
  if (tid < PREP_Z){
    g_cursor[tid] = 0;
    g_alps1[tid] = 0.f; g_alpd1[tid] = 0.f;
    g_alps2[tid] = 0.f; g_alpd2[tid] = 0.f;
    return;
  }
  int j = tid - PREP_Z;
  auto ld = [&](const void* p, int i) -> float {
    return isf32 ? ((const float*)p)[i] : bf2f(((const unsigned short*)p)[i]);
  };
  if (j < PREP_W1){
    float f = ld(ps.p[0], j);
    int k = j / C_HID, n = j % C_HID;
    int idx = wpack(k, n, C_HID);
    unsigned short h = f2bf(f);
    c_W1h[idx] = h; c_W1l[idx] = f2bf(f - bf2f(h));
    return;
  }
  j -= PREP_W1;
  if (j < PREP_W2){
    float f = ld(ps.p[4], j);
    int k = j / C_OUT, n = j % C_OUT;
    int idx = wpack(k, n, C_OUT);
    unsigned short h = f2bf(f);
    c_W2h[idx] = h; c_W2l[idx] = f2bf(f - bf2f(h));
    return;
  }
  j -= PREP_W2;
  if      (j <  256) c_as1f[j]        = ld(ps.p[1], j);
  else if (j <  512) c_ad1f[j - 256]  = ld(ps.p[2], j - 256);
  else if (j <  768) c_b1f [j - 512]  = ld(ps.p[3], j - 512);
  else if (j <  896) c_as2f[j - 768]  = ld(ps.p[5], j - 768);
  else if (j < 1024) c_ad2f[j - 896]  = ld(ps.p[6], j - 896);
  else if (j < 1152) c_b2f [j - 1024] = ld(ps.p[7], j - 1024);
}

// ---------------- split-bf16 MFMA GEMM + fused alpha epilogue (R13-proven) ----------------
// SEL=0: blocks [0,625) do gemm1; blocks [625,1875) scatter edges into the
// padded CSR (independent work, overlapped in one dispatch - saves a launch
// boundary and hides scatter under gemm).  SEL=1: pure gemm2.
template<int SEL>
__global__ __launch_bounds__(256) void gemm_k(const void* __restrict__ xsrc,
                                              const int* __restrict__ ei){
  if (SEL == 0 && blockIdx.x >= GEMM1_BLKS){   // ---- scatter part ----
    int e = (int)(blockIdx.x - GEMM1_BLKS) * 256 + (int)threadIdx.x;
    if (e < N_EDGES){
      int s, d;
      edge_sd(ei, e, s, d);
      int pos = atomicAdd(&g_cursor[d], 1);
      if (pos < CAP) g_srcidx[(size_t)d * CAP + pos] = s;  // clamp: memory-safe
    }
    return;
  }

  const int Nc = SEL ? C_OUT : C_HID;
  const int NT = SEL ? 2 : 4;
  const unsigned short* Wh = SEL ? c_W2h : c_W1h;
  const unsigned short* Wl = SEL ? c_W2l : c_W1l;
  unsigned short* Hb = SEL ? g_h2b : g_h1b;
  float* alps = SEL ? g_alps2 : g_alps1;
  float* alpd = SEL ? g_alpd2 : g_alpd1;
  const float* aS = SEL ? c_as2f : c_as1f;
  const float* aD = SEL ? c_ad2f : c_ad1f;
  const bool isf32 = (SEL == 0) && (g_isf32 != 0);

  int wave = (int)(threadIdx.x >> 6);
  int lane = (int)(threadIdx.x & 63);
  int kgrp = lane >> 4, cl = lane & 15;
  int mbase = blockIdx.x * 32;

  f32x4 acc[2][4];
#pragma unroll
  for (int m = 0; m < 2; ++m)
#pragma unroll
    for (int n = 0; n < NT; ++n) acc[m][n] = (f32x4){0.f, 0.f, 0.f, 0.f};

  for (int kt = 0; kt < 8; ++kt){
    int kbase = kt * 32 + kgrp * 8;
    bf16x8 ah[2], al[2];
    if (SEL == 1){
#pragma unroll
      for (int m = 0; m < 2; ++m){
        size_t ai = (size_t)(mbase + m * 16 + cl) * 256 + kbase;
        ah[m] = *(const bf16x8*)(g_g1h + ai);
        al[m] = *(const bf16x8*)(g_g1l + ai);
      }
    } else if (isf32){
      const float* Xf = (const float*)xsrc;
#pragma unroll
      for (int m = 0; m < 2; ++m){
        const float4* xp = (const float4*)(Xf + (size_t)(mbase + m * 16 + cl) * 256 + kbase);
        float4 v0 = xp[0], v1 = xp[1];
        float vals[8] = {v0.x, v0.y, v0.z, v0.w, v1.x, v1.y, v1.z, v1.w};
#pragma unroll
        for (int j = 0; j < 8; ++j){
          unsigned short h = f2bf(vals[j]);
          ah[m][j] = (short)h;
          al[m][j] = (short)f2bf(vals[j] - bf2f(h));
        }
      }
    } else {  // bf16 input: lo part is zero
      const unsigned short* Xb = (const unsigned short*)xsrc;
#pragma unroll
      for (int m = 0; m < 2; ++m){
        ah[m] = *(const bf16x8*)(Xb + (size_t)(mbase + m * 16 + cl) * 256 + kbase);
        al[m] = (bf16x8){0,0,0,0,0,0,0,0};
      }
    }
#pragma unroll
    for (int nn = 0; nn < NT; ++nn){
      int nt = wave * NT + nn;
      size_t wi = ((size_t)(kt * (Nc / 16) + nt) * 64 + lane) * 8;
      bf16x8 bh = *(const bf16x8*)(Wh + wi);
      bf16x8 bl = *(const bf16x8*)(Wl + wi);
#pragma unroll
      for (int m = 0; m < 2; ++m){
        acc[m][nn] = __builtin_amdgcn_mfma_f32_16x16x32_bf16(ah[m], bh, acc[m][nn], 0, 0, 0);
        acc[m][nn] = __builtin_amdgcn_mfma_f32_16x16x32_bf16(ah[m], bl, acc[m][nn], 0, 0, 0);
        acc[m][nn] = __builtin_amdgcn_mfma_f32_16x16x32_bf16(al[m], bh, acc[m][nn], 0, 0, 0);
      }
    }
  }

  float asv[4], adv[4];
#pragma unroll
  for (int nn = 0; nn < NT; ++nn){
    int col = (wave * NT + nn) * 16 + cl;
    asv[nn] = aS[col]; adv[nn] = aD[col];
  }
#pragma unroll
  for (int m = 0; m < 2; ++m){
#pragma unroll
    for (int i = 0; i < 4; ++i){
      int row = mbase + m * 16 + kgrp * 4 + i;
      float ps = 0.f, pd = 0.f;
#pragma unroll
      for (int nn = 0; nn < NT; ++nn){
        int col = (wave * NT + nn) * 16 + cl;
        float v = acc[m][nn][i];
        Hb[(size_t)row * Nc + col] = f2bf(v);
        ps += v * asv[nn]; pd += v * adv[nn];
      }
      ps += __shfl_xor(ps, 1);  pd += __shfl_xor(pd, 1);
      ps += __shfl_xor(ps, 2);  pd += __shfl_xor(pd, 2);
      ps += __shfl_xor(ps, 4);  pd += __shfl_xor(pd, 4);
      ps += __shfl_xor(ps, 8);  pd += __shfl_xor(pd, 8);
      if (cl == 0){
        atomicAdd(&alps[row], ps);
        atomicAdd(&alpd[row], pd);
      }
    }
  }
}

// ---------------- fused softmax + aggregation: one wave per node (R13-proven) ----------------
// Implicit self-loop added analytically (R15-proven); padded-CSR addressing.
#define ACC4(p, ww) { \
  a0 += (ww) * bf2f((unsigned short)((p).x & 0xFFFFu)); \
  a1 += (ww) * bf2f((unsigned short)((p).x >> 16)); \
  a2 += (ww) * bf2f((unsigned short)((p).y & 0xFFFFu)); \
  a3 += (ww) * bf2f((unsigned short)((p).y >> 16)); }

#define ACC2(p, ww) { \
  a0 += (ww) * bf2f((unsigned short)((p) & 0xFFFFu)); \
  a1 += (ww) * bf2f((unsigned short)((p) >> 16)); }

template<int F, int SEL>
__global__ void agg_k(float* OUT){
  const unsigned short* Hb = SEL ? g_h2b : g_h1b;
  const float* bias = SEL ? c_b2f : c_b1f;
  const float* alps = SEL ? g_alps2 : g_alps1;
  const float* alpd = SEL ? g_alpd2 : g_alpd1;
  int lane = threadIdx.x & 63;
  int n = blockIdx.x * 4 + (threadIdx.x >> 6);
  int len = g_cursor[n]; if (len > CAP) len = CAP;
  int i0 = n * CAP, i1 = i0 + len;
  float adn = alpd[n];
  float dpart = 0.f;
  float a0 = 0.f, a1 = 0.f, a2 = 0.f, a3 = 0.f;
  const uint2* H2 = (const uint2*)Hb;          // F=256: lane owns 4 feats
  const unsigned int* H1 = (const unsigned int*)Hb; // F=128: lane owns 2 feats

  { // implicit self-loop: source row = n
    float es = alps[n] + adn;
    es = (es > 0.f) ? es : NEG_SLOPE * es;
    float wself = __expf(es);
    if (lane == 0) dpart += wself;
    if constexpr (F == 256){
      uint2 p = H2[(size_t)n * 64 + lane];
      ACC4(p, wself)
    } else {
      unsigned int p = H1[(size_t)n * 64 + lane];
      ACC2(p, wself)
    }
  }

  for (int base = i0; base < i1; base += 64){
    int nv = i1 - base; if (nv > 64) nv = 64;
    int sv = 0; float wv = 0.f;
    if (lane < nv){
      sv = g_srcidx[base + lane];
      float e = alps[sv] + adn;
      e = (e > 0.f) ? e : NEG_SLOPE * e;
      wv = __expf(e);
    }
    dpart += wv;
    int j = 0;
    for (; j + 8 <= nv; j += 8){
      int s0 = __shfl(sv, j),     s1 = __shfl(sv, j + 1);
      int s2 = __shfl(sv, j + 2), s3 = __shfl(sv, j + 3);
      int s4 = __shfl(sv, j + 4), s5 = __shfl(sv, j + 5);
      int s6 = __shfl(sv, j + 6), s7 = __shfl(sv, j + 7);
      float w0 = __shfl(wv, j),     w1 = __shfl(wv, j + 1);
      float w2 = __shfl(wv, j + 2), w3 = __shfl(wv, j + 3);
      float w4 = __shfl(wv, j + 4), w5 = __shfl(wv, j + 5);
      float w6 = __shfl(wv, j + 6), w7 = __shfl(wv, j + 7);
      if constexpr (F == 256){
        uint2 p0 = H2[(size_t)s0 * 64 + lane];
        uint2 p1 = H2[(size_t)s1 * 64 + lane];
        uint2 p2 = H2[(size_t)s2 * 64 + lane];
        uint2 p3 = H2[(size_t)s3 * 64 + lane];
        uint2 p4 = H2[(size_t)s4 * 64 + lane];
        uint2 p5 = H2[(size_t)s5 * 64 + lane];
        uint2 p6 = H2[(size_t)s6 * 64 + lane];
        uint2 p7 = H2[(size_t)s7 * 64 + lane];
        ACC4(p0, w0) ACC4(p1, w1) ACC4(p2, w2) ACC4(p3, w3)
        ACC4(p4, w4) ACC4(p5, w5) ACC4(p6, w6) ACC4(p7, w7)
      } else {
        unsigned int p0 = H1[(size_t)s0 * 64 + lane];
        unsigned int p1 = H1[(size_t)s1 * 64 + lane];
        unsigned int p2 = H1[(size_t)s2 * 64 + lane];
        unsigned int p3 = H1[(size_t)s3 * 64 + lane];
        unsigned int p4 = H1[(size_t)s4 * 64 + lane];
        unsigned int p5 = H1[(size_t)s5 * 64 + lane];
        unsigned int p6 = H1[(size_t)s6 * 64 + lane];
        unsigned int p7 = H1[(size_t)s7 * 64 + lane];
        ACC2(p0, w0) ACC2(p1, w1) ACC2(p2, w2) ACC2(p3, w3)
        ACC2(p4, w4) ACC2(p5, w5) ACC2(p6, w6) ACC2(p7, w7)
      }
    }
    for (; j + 4 <= nv; j += 4){
      int s0 = __shfl(sv, j),     s1 = __shfl(sv, j + 1);
      int s2 = __shfl(sv, j + 2), s3 = __shfl(sv, j + 3);
      float w0 = __shfl(wv, j),     w1 = __shfl(wv, j + 1);
      float w2 = __shfl(wv, j + 2), w3 = __shfl(wv, j + 3);
      if constexpr (F == 256){
        uint2 p0 = H2[(size_t)s0 * 64 + lane];
        uint2 p1 = H2[(size_t)s1 * 64 + lane];
        uint2 p2 = H2[(size_t)s2 * 64 + lane];
        uint2 p3 = H2[(size_t)s3 * 64 + lane];
        ACC4(p0, w0) ACC4(p1, w1) ACC4(p2, w2) ACC4(p3, w3)
      } else {
        unsigned int p0 = H1[(size_t)s0 * 64 + lane];
        unsigned int p1 = H1[(size_t)s1 * 64 + lane];
        unsigned int p2 = H1[(size_t)s2 * 64 + lane];
        unsigned int p3 = H1[(size_t)s3 * 64 + lane];
        ACC2(p0, w0) ACC2(p1, w1) ACC2(p2, w2) ACC2(p3, w3)
      }
    }
    for (; j < nv; ++j){
      int s = __shfl(sv, j);
      float w = __shfl(wv, j);
      if constexpr (F == 256){
        uint2 p = H2[(size_t)s * 64 + lane];
        ACC4(p, w)
      } else {
        unsigned int p = H1[(size_t)s * 64 + lane];
        ACC2(p, w)
      }
    }
  }

  float den = dpart;
#pragma unroll
  for (int o = 32; o > 0; o >>= 1) den += __shfl_xor(den, o, 64);
  float inv = 1.f / den;

  if constexpr (F == 256){
    float o0 = a0 * inv + bias[4 * lane];
    float o1 = a1 * inv + bias[4 * lane + 1];
    float o2 = a2 * inv + bias[4 * lane + 2];
    float o3 = a3 * inv + bias[4 * lane + 3];
    if (SEL == 0){
      o0 = fmaxf(o0, 0.f); o1 = fmaxf(o1, 0.f);
      o2 = fmaxf(o2, 0.f); o3 = fmaxf(o3, 0.f);
      unsigned short h0 = f2bf(o0), h1 = f2bf(o1), h2 = f2bf(o2), h3 = f2bf(o3);
      uint2 ph, pl;
      ph.x = (unsigned)h0 | ((unsigned)h1 << 16);
      ph.y = (unsigned)h2 | ((unsigned)h3 << 16);
      pl.x = (unsigned)f2bf(o0 - bf2f(h0)) | ((unsigned)f2bf(o1 - bf2f(h1)) << 16);
      pl.y = (unsigned)f2bf(o2 - bf2f(h2)) | ((unsigned)f2bf(o3 - bf2f(h3)) << 16);
      ((uint2*)g_g1h)[(size_t)n * 64 + lane] = ph;
      ((uint2*)g_g1l)[(size_t)n * 64 + lane] = pl;
    } else {
      float4 o; o.x = o0; o.y = o1; o.z = o2; o.w = o3;
      ((float4*)OUT)[(size_t)n * 64 + lane] = o;
    }
  } else {
    float o0 = a0 * inv + bias[2 * lane];
    float o1 = a1 * inv + bias[2 * lane + 1];
    if (SEL == 0){
      o0 = fmaxf(o0, 0.f); o1 = fmaxf(o1, 0.f);
      unsigned short h0 = f2bf(o0), h1 = f2bf(o1);
      ((unsigned int*)g_g1h)[(size_t)n * 64 + lane] = (unsigned)h0 | ((unsigned)h1 << 16);
      ((unsigned int*)g_g1l)[(size_t)n * 64 + lane] =
        (unsigned)f2bf(o0 - bf2f(h0)) | ((unsigned)f2bf(o1 - bf2f(h1)) << 16);
    } else {
      float2 o; o.x = o0; o.y = o1;
      ((float2*)OUT)[(size_t)n * 64 + lane] = o;
    }
  }
}

extern "C" void kernel_launch(void* const* d_in, const int* in_sizes, int n_in,
                              void* d_out, int out_size, void* d_ws, size_t ws_size,
                              hipStream_t stream){
  (void)in_sizes; (void)n_in; (void)out_size; (void)d_ws; (void)ws_size;
  const void* x  = d_in[0];
  const int*  ei = (const int*)d_in[1];
  float* out = (float*)d_out;

  Ptrs ps;
  ps.p[0] = d_in[2]; ps.p[1] = d_in[3]; ps.p[2] = d_in[4]; ps.p[3] = d_in[5];
  ps.p[4] = d_in[6]; ps.p[5] = d_in[7]; ps.p[6] = d_in[8]; ps.p[7] = d_in[9];

  prep_k<<<(PREP_T + 255) / 256, 256, 0, stream>>>((const unsigned int*)x, ei, ps);

  // ---- layer 1 (gemm1 + scatter fused: independent work, one dispatch) ----
  gemm_k<0><<<GEMM1_BLKS + SCAT_BLKS, 256, 0, stream>>>(x, ei);
  agg_k<C_HID, 0><<<N_NODES / 4, 256, 0, stream>>>(nullptr);

  // ---- layer 2 ----
  gemm_k<1><<<N_NODES / 32, 256, 0, stream>>>(nullptr, nullptr);
  agg_k<C_OUT, 1><<<N_NODES / 4, 256, 0, stream>>>(out);
}